// Round 1
// baseline (5762.334 us; speedup 1.0000x reference)
//
#include <hip/hip_runtime.h>
#include <hip/hip_bf16.h>
#include <cstdint>

// Problem constants (fixed by reference): B=4, S=2048, DX=DM=1024, H=16, DK=64
constexpr int Bb = 4, Sq = 2048, DXc = 1024, DMc = 1024, NH = 16, DKc = 64;
constexpr int GM = Bb * Sq;  // 8192 rows in all GEMMs

__device__ inline float b2f(unsigned short u) {
  union { float f; uint32_t i; } c; c.i = ((uint32_t)u) << 16; return c.f;
}
__device__ inline unsigned short f2b(float f) {
  union { float f; uint32_t i; } c; c.f = f;
  uint32_t lsb = (c.i >> 16) & 1;
  c.i += 0x7fffu + lsb;               // round-to-nearest-even
  return (unsigned short)(c.i >> 16);
}

// ---------------------------------------------------------------------------
// Tiled f32 GEMM: C[M,N] = A[M,K] @ W[K,N] + bias[N]
// MODE 0: plain f32 output [M,N]
// MODE 1: bf16 output scattered to head-major [B,H,S,DK] (n -> (h,d))
// M=8192, N=K=1024 fixed. Tile 64x64, BK=16, 256 threads, 4x4 per thread.
// ---------------------------------------------------------------------------
template <int MODE>
__global__ __launch_bounds__(256) void gemm_k(
    const float* __restrict__ A, const float* __restrict__ W,
    const float* __restrict__ bias, float* __restrict__ outF,
    unsigned short* __restrict__ outB) {
  constexpr int K = 1024, N = 1024;
  __shared__ float As[16][64];  // As[k][m]
  __shared__ float Bs[16][64];  // Bs[k][n]
  const int tid = threadIdx.x;
  const int m0 = blockIdx.y * 64;
  const int n0 = blockIdx.x * 64;
  const int tx = tid & 15, ty = tid >> 4;
  const int arow = tid >> 2, acol = (tid & 3) << 2;   // A tile: 64 rows x 16 k
  const int brow = tid >> 4, bcol = (tid & 15) << 2;  // B tile: 16 k x 64 n
  float acc[4][4] = {};
  for (int k0 = 0; k0 < K; k0 += 16) {
    float4 av = *(const float4*)&A[(size_t)(m0 + arow) * K + k0 + acol];
    float4 bv = *(const float4*)&W[(size_t)(k0 + brow) * N + n0 + bcol];
    __syncthreads();  // previous iter's compute done before overwrite
    As[acol + 0][arow] = av.x; As[acol + 1][arow] = av.y;
    As[acol + 2][arow] = av.z; As[acol + 3][arow] = av.w;
    *(float4*)&Bs[brow][bcol] = bv;
    __syncthreads();
#pragma unroll
    for (int kk = 0; kk < 16; ++kk) {
      float4 a4 = *(const float4*)&As[kk][ty << 2];
      float4 b4 = *(const float4*)&Bs[kk][tx << 2];
      float ar[4] = {a4.x, a4.y, a4.z, a4.w};
      float br[4] = {b4.x, b4.y, b4.z, b4.w};
#pragma unroll
      for (int i = 0; i < 4; ++i)
#pragma unroll
        for (int j = 0; j < 4; ++j) acc[i][j] = fmaf(ar[i], br[j], acc[i][j]);
    }
  }
#pragma unroll
  for (int i = 0; i < 4; ++i) {
    const int m = m0 + (ty << 2) + i;
#pragma unroll
    for (int j = 0; j < 4; ++j) {
      const int n = n0 + (tx << 2) + j;
      const float v = acc[i][j] + bias[n];
      if (MODE == 0) {
        outF[(size_t)m * N + n] = v;
      } else {
        const int b = m >> 11;   // / Sq
        const int s = m & 2047;  // % Sq
        const int h = n >> 6;    // / DK
        const int d = n & 63;    // % DK
        outB[(((size_t)(b * NH + h) * Sq + s) << 6) + d] = f2b(v);
      }
    }
  }
}

// ---------------------------------------------------------------------------
// Causal attention, one block (256 thr) per (b*H+h, q-row).
// Q/K/V bf16 [B,H,S,DK]; Z f32 [B,S,DM]. Two-pass softmax, scores in LDS.
// ---------------------------------------------------------------------------
__global__ __launch_bounds__(256) void attn_k(
    const unsigned short* __restrict__ Q, const unsigned short* __restrict__ Kh,
    const unsigned short* __restrict__ Vh, float* __restrict__ Z) {
  __shared__ float qs[DKc];
  __shared__ float sc[Sq];
  __shared__ float part[4][DKc];
  __shared__ float red[5];
  const int tid = threadIdx.x;
  const int qrow = blockIdx.x;
  const int bh = blockIdx.y;
  const int L = qrow + 1;  // causal: attend to [0, qrow]
  const size_t base = (size_t)bh * Sq * DKc;

  if (tid < DKc) qs[tid] = b2f(Q[base + (size_t)qrow * DKc + tid]) * 0.125f;  // 1/sqrt(64)
  __syncthreads();

  // scores
  float lmax = -3.4e38f;
  for (int j = tid; j < L; j += 256) {
    const unsigned short* kr = Kh + base + (size_t)j * DKc;
    float dot = 0.f;
#pragma unroll
    for (int d = 0; d < DKc; d += 4) {
      ushort4 kv = *(const ushort4*)(kr + d);
      dot = fmaf(b2f(kv.x), qs[d + 0], dot);
      dot = fmaf(b2f(kv.y), qs[d + 1], dot);
      dot = fmaf(b2f(kv.z), qs[d + 2], dot);
      dot = fmaf(b2f(kv.w), qs[d + 3], dot);
    }
    sc[j] = dot;
    lmax = fmaxf(lmax, dot);
  }
  // block max
#pragma unroll
  for (int o = 32; o > 0; o >>= 1) lmax = fmaxf(lmax, __shfl_down(lmax, o, 64));
  if ((tid & 63) == 0) red[tid >> 6] = lmax;
  __syncthreads();
  if (tid == 0) red[4] = fmaxf(fmaxf(red[0], red[1]), fmaxf(red[2], red[3]));
  __syncthreads();
  const float mx = red[4];

  // exp + sum
  float lsum = 0.f;
  for (int j = tid; j < L; j += 256) {
    const float p = __expf(sc[j] - mx);
    sc[j] = p;
    lsum += p;
  }
#pragma unroll
  for (int o = 32; o > 0; o >>= 1) lsum += __shfl_down(lsum, o, 64);
  __syncthreads();  // everyone has read red[4]/sc before reuse
  if ((tid & 63) == 0) red[tid >> 6] = lsum;
  __syncthreads();
  if (tid == 0) red[4] = red[0] + red[1] + red[2] + red[3];
  __syncthreads();
  const float inv = 1.f / red[4];

  // P @ V: wave g handles j = g mod 4, lane d handles dim d (coalesced V reads)
  const int g = tid >> 6, d = tid & 63;
  float acc = 0.f;
  for (int j = g; j < L; j += 4)
    acc = fmaf(sc[j], b2f(Vh[base + (size_t)j * DKc + d]), acc);
  part[g][d] = acc;
  __syncthreads();
  if (tid < DKc) {
    const int b = bh >> 4;   // / NH
    const int h = bh & 15;   // % NH
    const float r = (part[0][tid] + part[1][tid] + part[2][tid] + part[3][tid]) * inv;
    Z[((size_t)b * Sq + qrow) * DMc + h * DKc + tid] = r;
  }
}

// ---------------------------------------------------------------------------
extern "C" void kernel_launch(void* const* d_in, const int* in_sizes, int n_in,
                              void* d_out, int out_size, void* d_ws, size_t ws_size,
                              hipStream_t stream) {
  const float* q  = (const float*)d_in[0];
  const float* k  = (const float*)d_in[1];
  const float* v  = (const float*)d_in[2];
  const float* wq = (const float*)d_in[3];
  const float* bq = (const float*)d_in[4];
  const float* wk = (const float*)d_in[5];
  const float* bk = (const float*)d_in[6];
  const float* wv = (const float*)d_in[7];
  const float* bv = (const float*)d_in[8];
  const float* wo = (const float*)d_in[9];
  const float* bo = (const float*)d_in[10];
  // d_in[11] = mask: causal tril by construction, handled analytically.

  unsigned short* qh = (unsigned short*)d_ws;           // [B,H,S,DK] bf16
  unsigned short* kh = qh + (size_t)GM * DMc;
  unsigned short* vh = kh + (size_t)GM * DMc;
  float* z = (float*)(vh + (size_t)GM * DMc);           // [B,S,DM] f32

  dim3 grid(DMc / 64, GM / 64);
  gemm_k<1><<<grid, 256, 0, stream>>>(q, wq, bq, nullptr, qh);
  gemm_k<1><<<grid, 256, 0, stream>>>(k, wk, bk, nullptr, kh);
  gemm_k<1><<<grid, 256, 0, stream>>>(v, wv, bv, nullptr, vh);
  attn_k<<<dim3(Sq, Bb * NH), 256, 0, stream>>>(qh, kh, vh, z);
  gemm_k<0><<<grid, 256, 0, stream>>>(z, wo, bo, (float*)d_out, nullptr);
}

// Round 2
// 1341.161 us; speedup vs baseline: 4.2965x; 4.2965x over previous
//
#include <hip/hip_runtime.h>
#include <hip/hip_bf16.h>
#include <cstdint>

// Problem constants (fixed by reference): B=4, S=2048, DX=DM=1024, H=16, DK=64
constexpr int Bb = 4, Sq = 2048, DXc = 1024, DMc = 1024, NH = 16, DKc = 64;
constexpr int GM = Bb * Sq;  // 8192 rows in all GEMMs

typedef __attribute__((ext_vector_type(8))) short short8;   // 8 bf16 (4 VGPRs)
typedef __attribute__((ext_vector_type(4))) float f32x4;    // MFMA C/D frag

__device__ inline float b2f(unsigned short u) {
  union { float f; uint32_t i; } c; c.i = ((uint32_t)u) << 16; return c.f;
}
__device__ inline unsigned short f2b(float f) {
  union { float f; uint32_t i; } c; c.f = f;
  uint32_t lsb = (c.i >> 16) & 1;
  c.i += 0x7fffu + lsb;               // round-to-nearest-even
  return (unsigned short)(c.i >> 16);
}

// ---------------------------------------------------------------------------
// Tiled f32 GEMM: C[M,N] = A[M,K] @ W[K,N] + bias[N]
// MODE 0: plain f32 output [M,N]
// MODE 1: bf16 output scattered to head-major [B,H,S,DK] (n -> (h,d))
// ---------------------------------------------------------------------------
template <int MODE>
__global__ __launch_bounds__(256) void gemm_k(
    const float* __restrict__ A, const float* __restrict__ W,
    const float* __restrict__ bias, float* __restrict__ outF,
    unsigned short* __restrict__ outB) {
  constexpr int K = 1024, N = 1024;
  __shared__ float As[16][64];  // As[k][m]
  __shared__ float Bs[16][64];  // Bs[k][n]
  const int tid = threadIdx.x;
  const int m0 = blockIdx.y * 64;
  const int n0 = blockIdx.x * 64;
  const int tx = tid & 15, ty = tid >> 4;
  const int arow = tid >> 2, acol = (tid & 3) << 2;
  const int brow = tid >> 4, bcol = (tid & 15) << 2;
  float acc[4][4] = {};
  for (int k0 = 0; k0 < K; k0 += 16) {
    float4 av = *(const float4*)&A[(size_t)(m0 + arow) * K + k0 + acol];
    float4 bv = *(const float4*)&W[(size_t)(k0 + brow) * N + n0 + bcol];
    __syncthreads();
    As[acol + 0][arow] = av.x; As[acol + 1][arow] = av.y;
    As[acol + 2][arow] = av.z; As[acol + 3][arow] = av.w;
    *(float4*)&Bs[brow][bcol] = bv;
    __syncthreads();
#pragma unroll
    for (int kk = 0; kk < 16; ++kk) {
      float4 a4 = *(const float4*)&As[kk][ty << 2];
      float4 b4 = *(const float4*)&Bs[kk][tx << 2];
      float ar[4] = {a4.x, a4.y, a4.z, a4.w};
      float br[4] = {b4.x, b4.y, b4.z, b4.w};
#pragma unroll
      for (int i = 0; i < 4; ++i)
#pragma unroll
        for (int j = 0; j < 4; ++j) acc[i][j] = fmaf(ar[i], br[j], acc[i][j]);
    }
  }
#pragma unroll
  for (int i = 0; i < 4; ++i) {
    const int m = m0 + (ty << 2) + i;
#pragma unroll
    for (int j = 0; j < 4; ++j) {
      const int n = n0 + (tx << 2) + j;
      const float v = acc[i][j] + bias[n];
      if (MODE == 0) {
        outF[(size_t)m * N + n] = v;
      } else {
        const int b = m >> 11;
        const int s = m & 2047;
        const int h = n >> 6;
        const int d = n & 63;
        outB[(((size_t)(b * NH + h) * Sq + s) << 6) + d] = f2b(v);
      }
    }
  }
}

// ---------------------------------------------------------------------------
// Flash attention with bf16 MFMA (16x16x32).
// Block = 256 thr (4 waves). Q-tile 64 rows (16/wave), K-tiles of 64.
// Q/K/V bf16 [B,H,S,DK]; Z f32 [B,S,DM]. Causal handled analytically.
// A-layout: A[m=lane&15][k=quad*8+j]; B-layout: B[k=quad*8+j][n=lane&15];
// C/D: col=lane&15, row=quad*4+reg.
// ---------------------------------------------------------------------------
__global__ __launch_bounds__(256) void flash_k(
    const unsigned short* __restrict__ Qh, const unsigned short* __restrict__ Kh,
    const unsigned short* __restrict__ Vh, float* __restrict__ Z) {
  constexpr int LD = 72;  // LDS row stride (bf16 elems), 144 B, 16B-aligned
  __shared__ __align__(16) unsigned short Klds[64 * LD];   // [key][dim]
  __shared__ __align__(16) unsigned short Vtlds[64 * LD];  // [dim][key] (transposed)
  __shared__ __align__(16) unsigned short Plds[64 * LD];   // [qrow][key], per-wave rows
  const int tid = threadIdx.x;
  const int w = tid >> 6, lane = tid & 63;
  const int quad = lane >> 4, l16 = lane & 15;
  const int bh = blockIdx.y;
  const int q0 = ((int)gridDim.x - 1 - (int)blockIdx.x) * 64;  // heavy blocks first
  const size_t base = (size_t)bh * Sq * DKc;

  // Q fragments: held in registers for the whole K loop
  short8 qf0, qf1;
  {
    const unsigned short* qp = Qh + base + (size_t)(q0 + w * 16 + l16) * DKc + quad * 8;
    qf0 = *(const short8*)(qp);
    qf1 = *(const short8*)(qp + 32);
  }

  float m_old[4], l_run[4];
  f32x4 oacc[4];
#pragma unroll
  for (int r = 0; r < 4; ++r) { m_old[r] = -3.4e38f; l_run[r] = 0.f; }
#pragma unroll
  for (int t = 0; t < 4; ++t) oacc[t] = (f32x4){0.f, 0.f, 0.f, 0.f};

  const int ntile = q0 / 64 + 1;
  for (int it = 0; it < ntile; ++it) {
    const int kt0 = it * 64;
    __syncthreads();  // previous iteration's LDS reads complete
    // ---- stage K tile (row copy, 512 x 16B) ----
    {
      const unsigned short* kg = Kh + base + (size_t)kt0 * DKc;
#pragma unroll
      for (int p = 0; p < 2; ++p) {
        const int c = tid + p * 256;
        const int row = c >> 3, seg = c & 7;
        *(uint4*)&Klds[row * LD + seg * 8] = *(const uint4*)(kg + row * 64 + seg * 8);
      }
      // ---- stage V transposed: wave w owns dims w*16..w*16+15, key = lane ----
      const unsigned short* vg = Vh + base + (size_t)(kt0 + lane) * DKc + w * 16;
      union { uint4 u4; unsigned short us[8]; } ua, ub;
      ua.u4 = *(const uint4*)vg;
      ub.u4 = *(const uint4*)(vg + 8);
#pragma unroll
      for (int i = 0; i < 8; ++i) {
        Vtlds[(w * 16 + i) * LD + lane] = ua.us[i];
        Vtlds[(w * 16 + 8 + i) * LD + lane] = ub.us[i];
      }
    }
    __syncthreads();

    // ---- S = Q K^T : 4 n-tiles of 16 keys ----
    f32x4 sacc[4];
#pragma unroll
    for (int t = 0; t < 4; ++t) {
      short8 kf0 = *(const short8*)&Klds[(t * 16 + l16) * LD + quad * 8];
      short8 kf1 = *(const short8*)&Klds[(t * 16 + l16) * LD + 32 + quad * 8];
      f32x4 z4 = (f32x4){0.f, 0.f, 0.f, 0.f};
      z4 = __builtin_amdgcn_mfma_f32_16x16x32_bf16(qf0, kf0, z4, 0, 0, 0);
      sacc[t] = __builtin_amdgcn_mfma_f32_16x16x32_bf16(qf1, kf1, z4, 0, 0, 0);
    }

    // ---- online softmax (registers, C-layout: row = quad*4+r, col = l16) ----
    const bool diag = (kt0 == q0);
    float p[4][4];  // [t][r]
    float mrow[4] = {-3.4e38f, -3.4e38f, -3.4e38f, -3.4e38f};
#pragma unroll
    for (int t = 0; t < 4; ++t)
#pragma unroll
      for (int r = 0; r < 4; ++r) {
        float s = sacc[t][r] * 0.125f;  // 1/sqrt(DK)
        if (diag && (t * 16 + l16 > w * 16 + quad * 4 + r)) s = -3.4e38f;
        p[t][r] = s;
        mrow[r] = fmaxf(mrow[r], s);
      }
#pragma unroll
    for (int r = 0; r < 4; ++r)
#pragma unroll
      for (int o = 1; o < 16; o <<= 1) mrow[r] = fmaxf(mrow[r], __shfl_xor(mrow[r], o, 64));
    float alpha[4], m_new[4];
#pragma unroll
    for (int r = 0; r < 4; ++r) {
      m_new[r] = fmaxf(m_old[r], mrow[r]);
      alpha[r] = __expf(m_old[r] - m_new[r]);
      m_old[r] = m_new[r];
    }
    float lsum[4] = {0.f, 0.f, 0.f, 0.f};
#pragma unroll
    for (int t = 0; t < 4; ++t)
#pragma unroll
      for (int r = 0; r < 4; ++r) {
        const float e = __expf(p[t][r] - m_new[r]);
        p[t][r] = e;
        lsum[r] += e;
      }
#pragma unroll
    for (int r = 0; r < 4; ++r) {
#pragma unroll
      for (int o = 1; o < 16; o <<= 1) lsum[r] += __shfl_xor(lsum[r], o, 64);
      l_run[r] = l_run[r] * alpha[r] + lsum[r];
    }
    // ---- P -> LDS (C-layout scatter, bf16); per-wave region, same-wave reads ----
#pragma unroll
    for (int t = 0; t < 4; ++t)
#pragma unroll
      for (int r = 0; r < 4; ++r)
        Plds[(w * 16 + quad * 4 + r) * LD + t * 16 + l16] = f2b(p[t][r]);
    // ---- rescale O ----
#pragma unroll
    for (int t = 0; t < 4; ++t)
#pragma unroll
      for (int r = 0; r < 4; ++r) oacc[t][r] *= alpha[r];
    // ---- O += P V : A-frag from Plds, B-frag from Vtlds ----
    short8 pf0 = *(const short8*)&Plds[(w * 16 + l16) * LD + quad * 8];
    short8 pf1 = *(const short8*)&Plds[(w * 16 + l16) * LD + 32 + quad * 8];
#pragma unroll
    for (int t = 0; t < 4; ++t) {
      short8 vf0 = *(const short8*)&Vtlds[(t * 16 + l16) * LD + quad * 8];
      short8 vf1 = *(const short8*)&Vtlds[(t * 16 + l16) * LD + 32 + quad * 8];
      oacc[t] = __builtin_amdgcn_mfma_f32_16x16x32_bf16(pf0, vf0, oacc[t], 0, 0, 0);
      oacc[t] = __builtin_amdgcn_mfma_f32_16x16x32_bf16(pf1, vf1, oacc[t], 0, 0, 0);
    }
  }

  // ---- epilogue: O / l -> Z f32 [B,S,DM] ----
  {
    const int b = bh >> 4, h = bh & 15;
#pragma unroll
    for (int r = 0; r < 4; ++r) {
      const float inv = 1.f / l_run[r];
      const int row = q0 + w * 16 + quad * 4 + r;
      float* zp = Z + ((size_t)b * Sq + row) * DMc + h * 64;
#pragma unroll
      for (int t = 0; t < 4; ++t) zp[t * 16 + l16] = oacc[t][r] * inv;
    }
  }
}

// ---------------------------------------------------------------------------
extern "C" void kernel_launch(void* const* d_in, const int* in_sizes, int n_in,
                              void* d_out, int out_size, void* d_ws, size_t ws_size,
                              hipStream_t stream) {
  const float* q  = (const float*)d_in[0];
  const float* k  = (const float*)d_in[1];
  const float* v  = (const float*)d_in[2];
  const float* wq = (const float*)d_in[3];
  const float* bq = (const float*)d_in[4];
  const float* wk = (const float*)d_in[5];
  const float* bk = (const float*)d_in[6];
  const float* wv = (const float*)d_in[7];
  const float* bv = (const float*)d_in[8];
  const float* wo = (const float*)d_in[9];
  const float* bo = (const float*)d_in[10];
  // d_in[11] = mask: causal tril by construction, handled analytically.

  unsigned short* qh = (unsigned short*)d_ws;           // [B,H,S,DK] bf16
  unsigned short* kh = qh + (size_t)GM * DMc;
  unsigned short* vh = kh + (size_t)GM * DMc;
  float* z = (float*)(vh + (size_t)GM * DMc);           // [B,S,DM] f32

  dim3 grid(DMc / 64, GM / 64);
  gemm_k<1><<<grid, 256, 0, stream>>>(q, wq, bq, nullptr, qh);
  gemm_k<1><<<grid, 256, 0, stream>>>(k, wk, bk, nullptr, kh);
  gemm_k<1><<<grid, 256, 0, stream>>>(v, wv, bv, nullptr, vh);
  flash_k<<<dim3(Sq / 64, Bb * NH), 256, 0, stream>>>(qh, kh, vh, z);
  gemm_k<0><<<grid, 256, 0, stream>>>(z, wo, bo, (float*)d_out, nullptr);
}

// Round 3
// 594.809 us; speedup vs baseline: 9.6877x; 2.2548x over previous
//
#include <hip/hip_runtime.h>
#include <hip/hip_bf16.h>
#include <cstdint>

// Problem constants (fixed by reference): B=4, S=2048, DX=DM=1024, H=16, DK=64
constexpr int Bb = 4, Sq = 2048, DXc = 1024, DMc = 1024, NH = 16, DKc = 64;
constexpr int GM = Bb * Sq;  // 8192 rows in all GEMMs

typedef __attribute__((ext_vector_type(8))) short short8;   // 8 bf16 (4 VGPRs)
typedef __attribute__((ext_vector_type(4))) float f32x4;    // MFMA C/D frag

__device__ inline float b2f(unsigned short u) {
  union { float f; uint32_t i; } c; c.i = ((uint32_t)u) << 16; return c.f;
}
__device__ inline unsigned short f2b(float f) {
  union { float f; uint32_t i; } c; c.f = f;
  uint32_t lsb = (c.i >> 16) & 1;
  c.i += 0x7fffu + lsb;               // round-to-nearest-even
  return (unsigned short)(c.i >> 16);
}

// async global->LDS, 16B per lane. LDS dest must be wave-uniform base + lane*16.
__device__ inline void load16_lds(const unsigned short* g, unsigned short* l) {
  __builtin_amdgcn_global_load_lds(
      (const __attribute__((address_space(1))) void*)g,
      (__attribute__((address_space(3))) void*)l, 16, 0, 0);
}

// ---------------------------------------------------------------------------
// f32 -> bf16 elementwise (float4 -> ushort4)
// ---------------------------------------------------------------------------
__global__ __launch_bounds__(256) void cvt_k(const float* __restrict__ in,
                                             unsigned short* __restrict__ out,
                                             int n4) {
  const int i = blockIdx.x * 256 + threadIdx.x;
  if (i < n4) {
    float4 v = ((const float4*)in)[i];
    ushort4 o;
    o.x = f2b(v.x); o.y = f2b(v.y); o.z = f2b(v.z); o.w = f2b(v.w);
    ((ushort4*)out)[i] = o;
  }
}

// ---------------------------------------------------------------------------
// W [K=1024, N=1024] f32 -> WT [N, K] bf16 (LDS-tiled 64x64 transpose)
// ---------------------------------------------------------------------------
__global__ __launch_bounds__(256) void wt_k(const float* __restrict__ W,
                                            unsigned short* __restrict__ WT) {
  __shared__ float t[64][65];
  const int tid = threadIdx.x;
  const int k0 = blockIdx.y * 64, n0 = blockIdx.x * 64;
#pragma unroll
  for (int p = 0; p < 4; ++p) {
    const int c = tid + p * 256;              // 0..1023
    const int r = c >> 4, c4 = (c & 15) << 2;
    float4 v = *(const float4*)&W[(size_t)(k0 + r) * 1024 + n0 + c4];
    t[r][c4 + 0] = v.x; t[r][c4 + 1] = v.y; t[r][c4 + 2] = v.z; t[r][c4 + 3] = v.w;
  }
  __syncthreads();
#pragma unroll
  for (int p = 0; p < 4; ++p) {
    const int c = tid + p * 256;
    const int n = c >> 4, k4 = (c & 15) << 2;
    ushort4 o;
    o.x = f2b(t[k4 + 0][n]); o.y = f2b(t[k4 + 1][n]);
    o.z = f2b(t[k4 + 2][n]); o.w = f2b(t[k4 + 3][n]);
    *(ushort4*)&WT[(size_t)(n0 + n) * 1024 + k0 + k4] = o;
  }
}

// ---------------------------------------------------------------------------
// bf16 MFMA GEMM: C[M,N] = A[M,K] @ BT[N,K]^T + bias.  M=8192, N=K=1024.
// 128x128 tile, BK=32, 256 thr (4 waves, 2x2), 4x4 frags of 16x16x32 per wave.
// global_load_lds width-16 staging; fragments via contiguous ds_read_b128.
// MODE 0: f32 out [M,N].  MODE 1: bf16 scatter to [B,H,S,DK].
// ---------------------------------------------------------------------------
template <int MODE>
__global__ __launch_bounds__(256) void mgemm_k(
    const unsigned short* __restrict__ A,   // [M,K] bf16 row-major
    const unsigned short* __restrict__ BT,  // [N,K] bf16 row-major
    const float* __restrict__ bias,         // [N] f32
    float* __restrict__ outF, unsigned short* __restrict__ outB) {
  constexpr int K = 1024;
  __shared__ __align__(16) unsigned short As[128 * 32];
  __shared__ __align__(16) unsigned short Bs[128 * 32];
  const int tid = threadIdx.x;
  const int lane = tid & 63;
  const int quad = lane >> 4, l16 = lane & 15;
  const int w = tid >> 6;
  const int wrow = (w >> 1) * 64, wcol = (w & 1) * 64;
  const int m0 = blockIdx.y * 128, n0 = blockIdx.x * 128;

  f32x4 acc[4][4];
#pragma unroll
  for (int i = 0; i < 4; ++i)
#pragma unroll
    for (int j = 0; j < 4; ++j) acc[i][j] = (f32x4){0.f, 0.f, 0.f, 0.f};

  for (int k0 = 0; k0 < K; k0 += 32) {
    __syncthreads();  // previous iteration's fragment reads complete
#pragma unroll
    for (int p = 0; p < 2; ++p) {
      const int c = tid + p * 256;            // chunk id, 0..511
      const int row = c >> 2, ks = (c & 3) << 3;
      load16_lds(&A[(size_t)(m0 + row) * K + k0 + ks], &As[c * 8]);
      load16_lds(&BT[(size_t)(n0 + row) * K + k0 + ks], &Bs[c * 8]);
    }
    __syncthreads();  // drains global_load_lds (vmcnt(0) before s_barrier)

    short8 af[4], bf[4];
#pragma unroll
    for (int i = 0; i < 4; ++i)
      af[i] = *(const short8*)&As[(wrow + i * 16 + l16) * 32 + quad * 8];
#pragma unroll
    for (int j = 0; j < 4; ++j)
      bf[j] = *(const short8*)&Bs[(wcol + j * 16 + l16) * 32 + quad * 8];
#pragma unroll
    for (int i = 0; i < 4; ++i)
#pragma unroll
      for (int j = 0; j < 4; ++j)
        acc[i][j] = __builtin_amdgcn_mfma_f32_16x16x32_bf16(af[i], bf[j], acc[i][j], 0, 0, 0);
  }

  // epilogue: bias + store. C/D layout: row = quad*4+r, col = l16 (per frag).
  float bv[4];
#pragma unroll
  for (int j = 0; j < 4; ++j) bv[j] = bias[n0 + wcol + j * 16 + l16];
#pragma unroll
  for (int i = 0; i < 4; ++i)
#pragma unroll
    for (int j = 0; j < 4; ++j)
#pragma unroll
      for (int r = 0; r < 4; ++r) {
        const int m = m0 + wrow + i * 16 + quad * 4 + r;
        const int n = n0 + wcol + j * 16 + l16;
        const float v = acc[i][j][r] + bv[j];
        if (MODE == 0) {
          outF[(size_t)m * 1024 + n] = v;
        } else {
          const int b = m >> 11, s = m & 2047, h = n >> 6, d = n & 63;
          outB[(((size_t)(b * NH + h) * Sq + s) << 6) + d] = f2b(v);
        }
      }
}

// ---------------------------------------------------------------------------
// Flash attention with bf16 MFMA (16x16x32). Z written as bf16 [B,S,DM].
// ---------------------------------------------------------------------------
__global__ __launch_bounds__(256) void flash_k(
    const unsigned short* __restrict__ Qh, const unsigned short* __restrict__ Kh,
    const unsigned short* __restrict__ Vh, unsigned short* __restrict__ Zb) {
  constexpr int LD = 72;  // LDS row stride (bf16 elems)
  __shared__ __align__(16) unsigned short Klds[64 * LD];   // [key][dim]
  __shared__ __align__(16) unsigned short Vtlds[64 * LD];  // [dim][key]
  __shared__ __align__(16) unsigned short Plds[64 * LD];   // [qrow][key]
  const int tid = threadIdx.x;
  const int w = tid >> 6, lane = tid & 63;
  const int quad = lane >> 4, l16 = lane & 15;
  const int bh = blockIdx.y;
  const int q0 = ((int)gridDim.x - 1 - (int)blockIdx.x) * 64;
  const size_t base = (size_t)bh * Sq * DKc;

  short8 qf0, qf1;
  {
    const unsigned short* qp = Qh + base + (size_t)(q0 + w * 16 + l16) * DKc + quad * 8;
    qf0 = *(const short8*)(qp);
    qf1 = *(const short8*)(qp + 32);
  }

  float m_old[4], l_run[4];
  f32x4 oacc[4];
#pragma unroll
  for (int r = 0; r < 4; ++r) { m_old[r] = -3.4e38f; l_run[r] = 0.f; }
#pragma unroll
  for (int t = 0; t < 4; ++t) oacc[t] = (f32x4){0.f, 0.f, 0.f, 0.f};

  const int ntile = q0 / 64 + 1;
  for (int it = 0; it < ntile; ++it) {
    const int kt0 = it * 64;
    __syncthreads();
    {
      const unsigned short* kg = Kh + base + (size_t)kt0 * DKc;
#pragma unroll
      for (int p = 0; p < 2; ++p) {
        const int c = tid + p * 256;
        const int row = c >> 3, seg = c & 7;
        *(uint4*)&Klds[row * LD + seg * 8] = *(const uint4*)(kg + row * 64 + seg * 8);
      }
      const unsigned short* vg = Vh + base + (size_t)(kt0 + lane) * DKc + w * 16;
      union { uint4 u4; unsigned short us[8]; } ua, ub;
      ua.u4 = *(const uint4*)vg;
      ub.u4 = *(const uint4*)(vg + 8);
#pragma unroll
      for (int i = 0; i < 8; ++i) {
        Vtlds[(w * 16 + i) * LD + lane] = ua.us[i];
        Vtlds[(w * 16 + 8 + i) * LD + lane] = ub.us[i];
      }
    }
    __syncthreads();

    f32x4 sacc[4];
#pragma unroll
    for (int t = 0; t < 4; ++t) {
      short8 kf0 = *(const short8*)&Klds[(t * 16 + l16) * LD + quad * 8];
      short8 kf1 = *(const short8*)&Klds[(t * 16 + l16) * LD + 32 + quad * 8];
      f32x4 z4 = (f32x4){0.f, 0.f, 0.f, 0.f};
      z4 = __builtin_amdgcn_mfma_f32_16x16x32_bf16(qf0, kf0, z4, 0, 0, 0);
      sacc[t] = __builtin_amdgcn_mfma_f32_16x16x32_bf16(qf1, kf1, z4, 0, 0, 0);
    }

    const bool diag = (kt0 == q0);
    float p[4][4];
    float mrow[4] = {-3.4e38f, -3.4e38f, -3.4e38f, -3.4e38f};
#pragma unroll
    for (int t = 0; t < 4; ++t)
#pragma unroll
      for (int r = 0; r < 4; ++r) {
        float s = sacc[t][r] * 0.125f;
        if (diag && (t * 16 + l16 > w * 16 + quad * 4 + r)) s = -3.4e38f;
        p[t][r] = s;
        mrow[r] = fmaxf(mrow[r], s);
      }
#pragma unroll
    for (int r = 0; r < 4; ++r)
#pragma unroll
      for (int o = 1; o < 16; o <<= 1) mrow[r] = fmaxf(mrow[r], __shfl_xor(mrow[r], o, 64));
    float alpha[4], m_new[4];
#pragma unroll
    for (int r = 0; r < 4; ++r) {
      m_new[r] = fmaxf(m_old[r], mrow[r]);
      alpha[r] = __expf(m_old[r] - m_new[r]);
      m_old[r] = m_new[r];
    }
    float lsum[4] = {0.f, 0.f, 0.f, 0.f};
#pragma unroll
    for (int t = 0; t < 4; ++t)
#pragma unroll
      for (int r = 0; r < 4; ++r) {
        const float e = __expf(p[t][r] - m_new[r]);
        p[t][r] = e;
        lsum[r] += e;
      }
#pragma unroll
    for (int r = 0; r < 4; ++r) {
#pragma unroll
      for (int o = 1; o < 16; o <<= 1) lsum[r] += __shfl_xor(lsum[r], o, 64);
      l_run[r] = l_run[r] * alpha[r] + lsum[r];
    }
#pragma unroll
    for (int t = 0; t < 4; ++t)
#pragma unroll
      for (int r = 0; r < 4; ++r)
        Plds[(w * 16 + quad * 4 + r) * LD + t * 16 + l16] = f2b(p[t][r]);
#pragma unroll
    for (int t = 0; t < 4; ++t)
#pragma unroll
      for (int r = 0; r < 4; ++r) oacc[t][r] *= alpha[r];
    short8 pf0 = *(const short8*)&Plds[(w * 16 + l16) * LD + quad * 8];
    short8 pf1 = *(const short8*)&Plds[(w * 16 + l16) * LD + 32 + quad * 8];
#pragma unroll
    for (int t = 0; t < 4; ++t) {
      short8 vf0 = *(const short8*)&Vtlds[(t * 16 + l16) * LD + quad * 8];
      short8 vf1 = *(const short8*)&Vtlds[(t * 16 + l16) * LD + 32 + quad * 8];
      oacc[t] = __builtin_amdgcn_mfma_f32_16x16x32_bf16(pf0, vf0, oacc[t], 0, 0, 0);
      oacc[t] = __builtin_amdgcn_mfma_f32_16x16x32_bf16(pf1, vf1, oacc[t], 0, 0, 0);
    }
  }

  {
    const int b = bh >> 4, h = bh & 15;
#pragma unroll
    for (int r = 0; r < 4; ++r) {
      const float inv = 1.f / l_run[r];
      const int row = q0 + w * 16 + quad * 4 + r;
      unsigned short* zp = Zb + ((size_t)b * Sq + row) * DMc + h * 64;
#pragma unroll
      for (int t = 0; t < 4; ++t) zp[t * 16 + l16] = f2b(oacc[t][r] * inv);
    }
  }
}

// ---------------------------------------------------------------------------
extern "C" void kernel_launch(void* const* d_in, const int* in_sizes, int n_in,
                              void* d_out, int out_size, void* d_ws, size_t ws_size,
                              hipStream_t stream) {
  const float* q  = (const float*)d_in[0];
  const float* k  = (const float*)d_in[1];
  const float* v  = (const float*)d_in[2];
  const float* wq = (const float*)d_in[3];
  const float* bq = (const float*)d_in[4];
  const float* wk = (const float*)d_in[5];
  const float* bk = (const float*)d_in[6];
  const float* wv = (const float*)d_in[7];
  const float* bv = (const float*)d_in[8];
  const float* wo = (const float*)d_in[9];
  const float* bo = (const float*)d_in[10];
  // d_in[11] = mask: causal tril by construction, handled analytically.

  constexpr size_t NEL = (size_t)GM * DMc;  // 8M elements
  unsigned short* qh  = (unsigned short*)d_ws;   // [B,H,S,DK] bf16
  unsigned short* kh  = qh + NEL;
  unsigned short* vh  = kh + NEL;
  unsigned short* xbf = vh + NEL;                // staging A bf16 / z bf16 (reused)
  unsigned short* wqt = xbf + NEL;               // WT bf16 [N,K] x4
  unsigned short* wkt = wqt + (size_t)DXc * DMc;
  unsigned short* wvt = wkt + (size_t)DXc * DMc;
  unsigned short* wot = wvt + (size_t)DXc * DMc;

  const dim3 tgrid(16, 16);
  wt_k<<<tgrid, 256, 0, stream>>>(wq, wqt);
  wt_k<<<tgrid, 256, 0, stream>>>(wk, wkt);
  wt_k<<<tgrid, 256, 0, stream>>>(wv, wvt);
  wt_k<<<tgrid, 256, 0, stream>>>(wo, wot);

  const int n4 = (int)(NEL / 4);
  const dim3 ggrid(DMc / 128, GM / 128);
  cvt_k<<<(n4 + 255) / 256, 256, 0, stream>>>(q, xbf, n4);
  mgemm_k<1><<<ggrid, 256, 0, stream>>>(xbf, wqt, bq, nullptr, qh);
  cvt_k<<<(n4 + 255) / 256, 256, 0, stream>>>(k, xbf, n4);
  mgemm_k<1><<<ggrid, 256, 0, stream>>>(xbf, wkt, bk, nullptr, kh);
  cvt_k<<<(n4 + 255) / 256, 256, 0, stream>>>(v, xbf, n4);
  mgemm_k<1><<<ggrid, 256, 0, stream>>>(xbf, wvt, bv, nullptr, vh);

  flash_k<<<dim3(Sq / 64, Bb * NH), 256, 0, stream>>>(qh, kh, vh, xbf);
  mgemm_k<0><<<ggrid, 256, 0, stream>>>(xbf, wot, bo, (float*)d_out, nullptr);
}